// Round 1
// baseline (467.201 us; speedup 1.0000x reference)
//
#include <hip/hip_runtime.h>
#include <stdint.h>

#define H_ 152
#define W_ 152
#define A_ 9
#define HW_ (H_ * W_)          // 23104
#define N_ (HW_ * A_)          // 207936
#define B_ 8
#define PRE_TOP 6000
#define POST_TOP 300
#define NBUCK 4096
#define CAND_CAP 8192
#define NMS_TH 0.7f

// ---------- helpers ----------

__device__ __forceinline__ unsigned fkey(float f) {
    unsigned u = __float_as_uint(f);
    return (u & 0x80000000u) ? ~u : (u | 0x80000000u);   // monotonic float->u32
}

// IoU suppression test, replicating reference op order exactly.
__device__ __forceinline__ bool sup_test(float ax1, float ay1, float ax2, float ay2, float aar,
                                         float bx1, float by1, float bx2, float by2, float bar) {
    float xx1 = fmaxf(ax1, bx1);
    float yy1 = fmaxf(ay1, by1);
    float xx2 = fminf(ax2, bx2);
    float yy2 = fminf(ay2, by2);
    float iw = fmaxf(xx2 - xx1 + 1.0f, 0.0f);
    float ih = fmaxf(yy2 - yy1 + 1.0f, 0.0f);
    float inter = __fmul_rn(iw, ih);
    float iou = inter / (aar + bar - inter);
    return iou > NMS_TH;
}

// ---------- kernels ----------

__global__ void zero_k(unsigned* p, int n) {
    int i = blockIdx.x * blockDim.x + threadIdx.x;
    int st = gridDim.x * blockDim.x;
    for (; i < n; i += st) p[i] = 0;
}

__global__ void hist_k(const float* __restrict__ scores, unsigned* __restrict__ hist) {
    __shared__ unsigned lh[NBUCK];
    int b = blockIdx.y;
    for (int i = threadIdx.x; i < NBUCK; i += blockDim.x) lh[i] = 0;
    __syncthreads();
    // channels 9..17 are contiguous: element e in [0,N) maps linearly
    const float* sb = scores + ((size_t)b * 18 + A_) * HW_;
    int stride = gridDim.x * blockDim.x;
    for (int e = blockIdx.x * blockDim.x + threadIdx.x; e < N_; e += stride) {
        atomicAdd(&lh[fkey(sb[e]) >> 20], 1u);
    }
    __syncthreads();
    for (int i = threadIdx.x; i < NBUCK; i += blockDim.x) {
        unsigned v = lh[i];
        if (v) atomicAdd(&hist[b * NBUCK + i], v);
    }
}

__global__ void scan_k(const unsigned* __restrict__ hist, unsigned* __restrict__ bucketT) {
    __shared__ unsigned ps[1024];
    int b = blockIdx.x, t = threadIdx.x;
    const unsigned* hb = hist + b * NBUCK;
    // reverse order: r = 0 is the TOP bucket (4095)
    unsigned c0 = hb[4095 - (4 * t + 0)];
    unsigned c1 = hb[4095 - (4 * t + 1)];
    unsigned c2 = hb[4095 - (4 * t + 2)];
    unsigned c3 = hb[4095 - (4 * t + 3)];
    unsigned local = c0 + c1 + c2 + c3;
    ps[t] = local;
    __syncthreads();
    for (int off = 1; off < 1024; off <<= 1) {
        unsigned v = (t >= off) ? ps[t - off] : 0u;
        __syncthreads();
        ps[t] += v;
        __syncthreads();
    }
    unsigned incl = ps[t], excl = incl - local;
    if (excl < PRE_TOP && incl >= PRE_TOP) {
        unsigned cum = excl;
        unsigned cc[4] = {c0, c1, c2, c3};
        for (int k = 0; k < 4; ++k) {
            cum += cc[k];
            if (cum >= PRE_TOP) { bucketT[b] = (unsigned)(4095 - (4 * t + k)); break; }
        }
    }
    if (t == 1023 && ps[1023] < PRE_TOP) bucketT[b] = 0;  // safety: include everything
}

__global__ void compact_k(const float* __restrict__ scores, const unsigned* __restrict__ bucketT,
                          unsigned* __restrict__ cnt, uint2* __restrict__ cand) {
    int b = blockIdx.y;
    const float* sb = scores + ((size_t)b * 18 + A_) * HW_;
    unsigned T = bucketT[b];
    int lane = threadIdx.x & 63;
    int stride = gridDim.x * blockDim.x;
    for (int base = blockIdx.x * blockDim.x; base < N_; base += stride) {
        int e = base + threadIdx.x;
        bool pred = false;
        unsigned key = 0, n = 0;
        if (e < N_) {
            key = fkey(sb[e]);
            if ((key >> 20) >= T) {
                pred = true;
                int a = e / HW_;
                int pix = e - a * HW_;
                n = (unsigned)(pix * A_ + a);   // index in reference (h*W+w)*A + a order
            }
        }
        unsigned long long m = __ballot(pred);
        if (m) {
            int ldr = __ffsll((long long)m) - 1;
            int basep = 0;
            if (lane == ldr) basep = (int)atomicAdd(&cnt[b], (unsigned)__popcll(m));
            basep = __shfl(basep, ldr);
            if (pred) {
                unsigned pos = (unsigned)basep + (unsigned)__popcll(m & ((1ull << lane) - 1ull));
                if (pos < CAND_CAP) cand[(size_t)b * CAND_CAP + pos] = make_uint2(key, n);
            }
        }
    }
}

__global__ void __launch_bounds__(1024) sort_k(const unsigned* __restrict__ cnt,
                                               const uint2* __restrict__ cand,
                                               const float* __restrict__ deltas,
                                               const float* __restrict__ anchors,
                                               const float* __restrict__ im_info,
                                               float4* __restrict__ boxes) {
    __shared__ unsigned long long s[CAND_CAP];   // 64 KiB
    int b = blockIdx.x, t = threadIdx.x;
    int M = min((int)cnt[b], CAND_CAP);
    for (int i = t; i < CAND_CAP; i += blockDim.x) {
        if (i < M) {
            uint2 c = cand[(size_t)b * CAND_CAP + i];
            s[i] = ((unsigned long long)c.x << 32) | (unsigned)(~c.y);  // key desc, idx asc
        } else {
            s[i] = 0ull;
        }
    }
    __syncthreads();
    // bitonic sort, descending
    for (int k = 2; k <= CAND_CAP; k <<= 1) {
        for (int j = k >> 1; j > 0; j >>= 1) {
            for (int i = t; i < CAND_CAP; i += blockDim.x) {
                int ixj = i ^ j;
                if (ixj > i) {
                    unsigned long long a = s[i], c = s[ixj];
                    bool up = ((i & k) == 0);
                    if (up ? (a < c) : (a > c)) { s[i] = c; s[ixj] = a; }
                }
            }
            __syncthreads();
        }
    }
    // decode boxes for top PRE_TOP
    float hmax = im_info[b * 3 + 0] - 1.0f;
    float wmax = im_info[b * 3 + 1] - 1.0f;
    const float* db = deltas + (size_t)b * 36 * HW_;
    for (int sl = t; sl < PRE_TOP; sl += blockDim.x) {
        if (sl < M) {
            unsigned n = ~(unsigned)(s[sl] & 0xffffffffull);
            int a = (int)(n % A_);
            int pix = (int)(n / A_);
            int w = pix % W_, h = pix / W_;
            float sx = (float)(w * 16), sy = (float)(h * 16);
            float ax1 = anchors[a * 4 + 0] + sx;
            float ay1 = anchors[a * 4 + 1] + sy;
            float ax2 = anchors[a * 4 + 2] + sx;
            float ay2 = anchors[a * 4 + 3] + sy;
            float ww = ax2 - ax1 + 1.0f;
            float hh = ay2 - ay1 + 1.0f;
            float ctx = ax1 + 0.5f * ww;
            float cty = ay1 + 0.5f * hh;
            int didx = (4 * a) * HW_ + pix;
            float dx = db[didx];
            float dy = db[didx + HW_];
            float dw = db[didx + 2 * HW_];
            float dh = db[didx + 3 * HW_];
            float pcx = __fadd_rn(__fmul_rn(dx, ww), ctx);   // no FMA contraction (match np)
            float pcy = __fadd_rn(__fmul_rn(dy, hh), cty);
            float pw = __fmul_rn(expf(dw), ww);
            float ph = __fmul_rn(expf(dh), hh);
            float x1 = pcx - 0.5f * pw;
            float y1 = pcy - 0.5f * ph;
            float x2 = pcx + 0.5f * pw;
            float y2 = pcy + 0.5f * ph;
            x1 = fminf(fmaxf(x1, 0.0f), wmax);
            y1 = fminf(fmaxf(y1, 0.0f), hmax);
            x2 = fminf(fmaxf(x2, 0.0f), wmax);
            y2 = fminf(fmaxf(y2, 0.0f), hmax);
            boxes[(size_t)b * PRE_TOP + sl] = make_float4(x1, y1, x2, y2);
        } else {
            boxes[(size_t)b * PRE_TOP + sl] = make_float4(0.f, 0.f, 0.f, 0.f);
        }
    }
}

__global__ void __launch_bounds__(1024) nms_k(const float4* __restrict__ boxes,
                                              float* __restrict__ out) {
    __shared__ float kx1[POST_TOP], ky1[POST_TOP], kx2[POST_TOP], ky2[POST_TOP], kar[POST_TOP];
    __shared__ float gx1[64], gy1[64], gx2[64], gy2[64], gar[64];
    __shared__ unsigned extw[2];
    __shared__ unsigned intraw[128];
    __shared__ unsigned long long s_keep;
    __shared__ int s_base, s_kc, s_done;
    int b = blockIdx.x, t = threadIdx.x;
    if (t == 0) { s_kc = 0; s_done = 0; }
    const float4* bb = boxes + (size_t)b * PRE_TOP;
    const int ngroups = (PRE_TOP + 63) / 64;

    for (int g = 0; g < ngroups; ++g) {
        __syncthreads();          // prev append + flags visible
        if (s_done) break;
        int gbase = g * 64;
        int gsz = min(64, PRE_TOP - gbase);
        if (t < gsz) {
            float4 v = bb[gbase + t];
            gx1[t] = v.x; gy1[t] = v.y; gx2[t] = v.z; gy2[t] = v.w;
            gar[t] = __fmul_rn(v.z - v.x + 1.0f, v.w - v.y + 1.0f);
        }
        if (t < 2) extw[t] = 0u;
        if (t < 128) intraw[t] = 0u;
        __syncthreads();

        int kc = s_kc;
        // external suppression vs kept list
        {
            int j = t >> 4, sub = t & 15;
            if (j < gsz) {
                float ax1 = gx1[j], ay1 = gy1[j], ax2 = gx2[j], ay2 = gy2[j], aar = gar[j];
                bool any = false;
                for (int kk = sub; kk < kc; kk += 16) {
                    if (sup_test(kx1[kk], ky1[kk], kx2[kk], ky2[kk], kar[kk],
                                 ax1, ay1, ax2, ay2, aar)) { any = true; break; }
                }
                if (any) atomicOr(&extw[j >> 5], 1u << (j & 31));
            }
        }
        // intra-group pairwise (jj earlier suppresses ll later)
        for (int p = t; p < 4096; p += 1024) {
            int jj = p >> 6, ll = p & 63;
            if (jj < ll && ll < gsz) {
                if (sup_test(gx1[jj], gy1[jj], gx2[jj], gy2[jj], gar[jj],
                             gx1[ll], gy1[ll], gx2[ll], gy2[ll], gar[ll])) {
                    atomicOr(&intraw[2 * jj + (ll >> 5)], 1u << (ll & 31));
                }
            }
        }
        __syncthreads();

        if (t == 0) {
            unsigned long long ext64 = (unsigned long long)extw[0] |
                                       ((unsigned long long)extw[1] << 32);
            unsigned long long valid = (gsz >= 64) ? ~0ull : ((1ull << gsz) - 1ull);
            unsigned long long alive = (~ext64) & valid;
            unsigned long long keep = 0ull;
            int kcc = s_kc;
            s_base = kcc;
            while (alive && kcc < POST_TOP) {
                int j = __ffsll((long long)alive) - 1;
                keep |= (1ull << j);
                ++kcc;
                unsigned long long row = (unsigned long long)intraw[2 * j] |
                                         ((unsigned long long)intraw[2 * j + 1] << 32);
                alive &= ~row;
                alive &= ~(1ull << j);
            }
            s_keep = keep;
            s_kc = kcc;
            if (kcc >= POST_TOP) s_done = 1;
        }
        __syncthreads();

        if (t < gsz && ((s_keep >> t) & 1ull)) {
            int rank = __popcll(s_keep & ((1ull << t) - 1ull));
            int slot = s_base + rank;
            kx1[slot] = gx1[t]; ky1[slot] = gy1[t];
            kx2[slot] = gx2[t]; ky2[slot] = gy2[t]; kar[slot] = gar[t];
            float* o = out + (size_t)(b * POST_TOP + slot) * 5;
            o[0] = (float)b; o[1] = gx1[t]; o[2] = gy1[t]; o[3] = gx2[t]; o[4] = gy2[t];
        }
    }
    __syncthreads();
    for (int sl = s_kc + t; sl < POST_TOP; sl += 1024) {
        float* o = out + (size_t)(b * POST_TOP + sl) * 5;
        o[0] = (float)b; o[1] = 0.f; o[2] = 0.f; o[3] = 0.f; o[4] = 0.f;
    }
}

// ---------- launch ----------

extern "C" void kernel_launch(void* const* d_in, const int* in_sizes, int n_in,
                              void* d_out, int out_size, void* d_ws, size_t ws_size,
                              hipStream_t stream) {
    const float* scores  = (const float*)d_in[0];   // (8, 18, 152, 152)
    const float* deltas  = (const float*)d_in[1];   // (8, 36, 152, 152)
    const float* im_info = (const float*)d_in[2];   // (8, 3)
    const float* anchors = (const float*)d_in[3];   // (9, 4)
    float* out = (float*)d_out;                     // (8, 300, 5)

    // workspace layout (bytes)
    unsigned* hist    = (unsigned*)d_ws;                                 // 8*4096*4 = 131072
    unsigned* cnt     = hist + B_ * NBUCK;                               // +32
    unsigned* bucketT = cnt + B_;                                        // +32
    uint2*    cand    = (uint2*)((char*)d_ws + 131136);                  // 8*8192*8 = 524288
    float4*   boxes   = (float4*)((char*)d_ws + 655424);                 // 8*6000*16 = 768000
    // total ~1.39 MB

    zero_k<<<64, 256, 0, stream>>>((unsigned*)d_ws, B_ * NBUCK + 2 * B_);
    hist_k<<<dim3(128, B_), 256, 0, stream>>>(scores, hist);
    scan_k<<<B_, 1024, 0, stream>>>(hist, bucketT);
    compact_k<<<dim3(64, B_), 256, 0, stream>>>(scores, bucketT, cnt, cand);
    sort_k<<<B_, 1024, 0, stream>>>(cnt, cand, deltas, anchors, im_info, boxes);
    nms_k<<<B_, 1024, 0, stream>>>(boxes, out);
}

// Round 2
// 215.758 us; speedup vs baseline: 2.1654x; 2.1654x over previous
//
#include <hip/hip_runtime.h>
#include <stdint.h>

#define H_ 152
#define W_ 152
#define A_ 9
#define HW_ (H_ * W_)          // 23104
#define N_ (HW_ * A_)          // 207936
#define B_ 8
#define PRE_TOP 6000
#define POST_TOP 300
#define NBUCK 4096
#define CAND_CAP 8192
#define NMS_TH 0.7f
#define CNT_STRIDE 32          // pad per-batch counters to 128 B

// ---------- helpers ----------

__device__ __forceinline__ unsigned fkey(float f) {
    unsigned u = __float_as_uint(f);
    return (u & 0x80000000u) ? ~u : (u | 0x80000000u);   // monotonic float->u32
}

// IoU suppression test, replicating reference op order exactly.
__device__ __forceinline__ bool sup_test(float ax1, float ay1, float ax2, float ay2, float aar,
                                         float bx1, float by1, float bx2, float by2, float bar) {
    float xx1 = fmaxf(ax1, bx1);
    float yy1 = fmaxf(ay1, by1);
    float xx2 = fminf(ax2, bx2);
    float yy2 = fminf(ay2, by2);
    float iw = fmaxf(xx2 - xx1 + 1.0f, 0.0f);
    float ih = fmaxf(yy2 - yy1 + 1.0f, 0.0f);
    float inter = __fmul_rn(iw, ih);
    float iou = inter / (aar + bar - inter);
    return iou > NMS_TH;
}

// ---------- kernels ----------

__global__ void zero_k(unsigned* p, int n) {
    int i = blockIdx.x * blockDim.x + threadIdx.x;
    int st = gridDim.x * blockDim.x;
    for (; i < n; i += st) p[i] = 0;
}

__global__ void hist_k(const float* __restrict__ scores, unsigned* __restrict__ hist) {
    __shared__ unsigned lh[NBUCK];
    int b = blockIdx.y;
    for (int i = threadIdx.x; i < NBUCK; i += blockDim.x) lh[i] = 0;
    __syncthreads();
    const float4* sb = (const float4*)(scores + ((size_t)b * 18 + A_) * HW_);
    const int N4 = N_ / 4;                      // 51984
    int stride = gridDim.x * blockDim.x;
    for (int e = blockIdx.x * blockDim.x + threadIdx.x; e < N4; e += stride) {
        float4 v = sb[e];
        atomicAdd(&lh[fkey(v.x) >> 20], 1u);
        atomicAdd(&lh[fkey(v.y) >> 20], 1u);
        atomicAdd(&lh[fkey(v.z) >> 20], 1u);
        atomicAdd(&lh[fkey(v.w) >> 20], 1u);
    }
    __syncthreads();
    for (int i = threadIdx.x; i < NBUCK; i += blockDim.x) {
        unsigned v = lh[i];
        if (v) atomicAdd(&hist[b * NBUCK + i], v);
    }
}

__global__ void scan_k(const unsigned* __restrict__ hist, unsigned* __restrict__ bucketT) {
    __shared__ unsigned ps[1024];
    int b = blockIdx.x, t = threadIdx.x;
    const unsigned* hb = hist + b * NBUCK;
    unsigned c0 = hb[4095 - (4 * t + 0)];
    unsigned c1 = hb[4095 - (4 * t + 1)];
    unsigned c2 = hb[4095 - (4 * t + 2)];
    unsigned c3 = hb[4095 - (4 * t + 3)];
    unsigned local = c0 + c1 + c2 + c3;
    ps[t] = local;
    __syncthreads();
    for (int off = 1; off < 1024; off <<= 1) {
        unsigned v = (t >= off) ? ps[t - off] : 0u;
        __syncthreads();
        ps[t] += v;
        __syncthreads();
    }
    unsigned incl = ps[t], excl = incl - local;
    if (excl < PRE_TOP && incl >= PRE_TOP) {
        unsigned cum = excl;
        unsigned cc[4] = {c0, c1, c2, c3};
        for (int k = 0; k < 4; ++k) {
            cum += cc[k];
            if (cum >= PRE_TOP) { bucketT[b] = (unsigned)(4095 - (4 * t + k)); break; }
        }
    }
    if (t == 1023 && ps[1023] < PRE_TOP) bucketT[b] = 0;  // safety: include everything
}

__global__ void compact_k(const float* __restrict__ scores, const unsigned* __restrict__ bucketT,
                          unsigned* __restrict__ cnt, uint2* __restrict__ cand) {
    __shared__ unsigned wtot[4], wbase[4];
    __shared__ unsigned blkbase;
    int b = blockIdx.y;
    const float4* sb = (const float4*)(scores + ((size_t)b * 18 + A_) * HW_);
    unsigned T = bucketT[b];
    int lane = threadIdx.x & 63;
    int wid = threadIdx.x >> 6;
    const int N4 = N_ / 4;                       // 51984
    int stride = gridDim.x * blockDim.x;
    int niters = (N4 + stride - 1) / stride;
    unsigned long long lower = (lane == 63) ? 0x7fffffffffffffffull
                                            : ((1ull << lane) - 1ull);
    for (int it = 0; it < niters; ++it) {
        int e = it * stride + blockIdx.x * (int)blockDim.x + (int)threadIdx.x;
        bool p0 = false, p1 = false, p2 = false, p3 = false;
        unsigned k0 = 0, k1 = 0, k2 = 0, k3 = 0;
        if (e < N4) {
            float4 v = sb[e];
            k0 = fkey(v.x); k1 = fkey(v.y); k2 = fkey(v.z); k3 = fkey(v.w);
            p0 = (k0 >> 20) >= T; p1 = (k1 >> 20) >= T;
            p2 = (k2 >> 20) >= T; p3 = (k3 >> 20) >= T;
        }
        unsigned long long m0 = __ballot(p0), m1 = __ballot(p1);
        unsigned long long m2 = __ballot(p2), m3 = __ballot(p3);
        unsigned t0 = (unsigned)__popcll(m0), t1 = (unsigned)__popcll(m1);
        unsigned t2 = (unsigned)__popcll(m2), t3 = (unsigned)__popcll(m3);
        unsigned wtotal = t0 + t1 + t2 + t3;
        if (lane == 0) wtot[wid] = wtotal;
        __syncthreads();
        if (threadIdx.x == 0) {
            unsigned s0 = wtot[0], s1 = wtot[1], s2 = wtot[2], s3 = wtot[3];
            unsigned tot = s0 + s1 + s2 + s3;
            blkbase = tot ? atomicAdd(&cnt[b * CNT_STRIDE], tot) : 0u;
            wbase[0] = 0; wbase[1] = s0; wbase[2] = s0 + s1; wbase[3] = s0 + s1 + s2;
        }
        __syncthreads();
        if (wtotal) {
            unsigned base = blkbase + wbase[wid];
            unsigned o0 = base + (unsigned)__popcll(m0 & lower);
            unsigned o1 = base + t0 + (unsigned)__popcll(m1 & lower);
            unsigned o2 = base + t0 + t1 + (unsigned)__popcll(m2 & lower);
            unsigned o3 = base + t0 + t1 + t2 + (unsigned)__popcll(m3 & lower);
            uint2* cb = cand + (size_t)b * CAND_CAP;
            int e4 = e * 4;
            if (p0 && o0 < CAND_CAP) {
                int a = (e4 + 0) / HW_, pix = (e4 + 0) - a * HW_;
                cb[o0] = make_uint2(k0, (unsigned)(pix * A_ + a));
            }
            if (p1 && o1 < CAND_CAP) {
                int a = (e4 + 1) / HW_, pix = (e4 + 1) - a * HW_;
                cb[o1] = make_uint2(k1, (unsigned)(pix * A_ + a));
            }
            if (p2 && o2 < CAND_CAP) {
                int a = (e4 + 2) / HW_, pix = (e4 + 2) - a * HW_;
                cb[o2] = make_uint2(k2, (unsigned)(pix * A_ + a));
            }
            if (p3 && o3 < CAND_CAP) {
                int a = (e4 + 3) / HW_, pix = (e4 + 3) - a * HW_;
                cb[o3] = make_uint2(k3, (unsigned)(pix * A_ + a));
            }
        }
    }
}

__global__ void __launch_bounds__(1024) sort_k(const unsigned* __restrict__ cnt,
                                               const uint2* __restrict__ cand,
                                               const float* __restrict__ deltas,
                                               const float* __restrict__ anchors,
                                               const float* __restrict__ im_info,
                                               float4* __restrict__ boxes) {
    __shared__ unsigned long long s[CAND_CAP];   // 64 KiB
    int b = blockIdx.x, t = threadIdx.x;
    int M = min((int)cnt[b * CNT_STRIDE], CAND_CAP);
    for (int i = t; i < CAND_CAP; i += blockDim.x) {
        if (i < M) {
            uint2 c = cand[(size_t)b * CAND_CAP + i];
            s[i] = ((unsigned long long)c.x << 32) | (unsigned)(~c.y);  // key desc, idx asc
        } else {
            s[i] = 0ull;
        }
    }
    __syncthreads();
    // bitonic sort, descending
    for (int k = 2; k <= CAND_CAP; k <<= 1) {
        for (int j = k >> 1; j > 0; j >>= 1) {
            for (int i = t; i < CAND_CAP; i += blockDim.x) {
                int ixj = i ^ j;
                if (ixj > i) {
                    unsigned long long a = s[i], c = s[ixj];
                    bool up = ((i & k) == 0);
                    if (up ? (a < c) : (a > c)) { s[i] = c; s[ixj] = a; }
                }
            }
            __syncthreads();
        }
    }
    // decode boxes for top PRE_TOP
    float hmax = im_info[b * 3 + 0] - 1.0f;
    float wmax = im_info[b * 3 + 1] - 1.0f;
    const float* db = deltas + (size_t)b * 36 * HW_;
    for (int sl = t; sl < PRE_TOP; sl += blockDim.x) {
        if (sl < M) {
            unsigned n = ~(unsigned)(s[sl] & 0xffffffffull);
            int a = (int)(n % A_);
            int pix = (int)(n / A_);
            int w = pix % W_, h = pix / W_;
            float sx = (float)(w * 16), sy = (float)(h * 16);
            float ax1 = anchors[a * 4 + 0] + sx;
            float ay1 = anchors[a * 4 + 1] + sy;
            float ax2 = anchors[a * 4 + 2] + sx;
            float ay2 = anchors[a * 4 + 3] + sy;
            float ww = ax2 - ax1 + 1.0f;
            float hh = ay2 - ay1 + 1.0f;
            float ctx = ax1 + 0.5f * ww;
            float cty = ay1 + 0.5f * hh;
            int didx = (4 * a) * HW_ + pix;
            float dx = db[didx];
            float dy = db[didx + HW_];
            float dw = db[didx + 2 * HW_];
            float dh = db[didx + 3 * HW_];
            float pcx = __fadd_rn(__fmul_rn(dx, ww), ctx);   // no FMA contraction (match np)
            float pcy = __fadd_rn(__fmul_rn(dy, hh), cty);
            float pw = __fmul_rn(expf(dw), ww);
            float ph = __fmul_rn(expf(dh), hh);
            float x1 = pcx - 0.5f * pw;
            float y1 = pcy - 0.5f * ph;
            float x2 = pcx + 0.5f * pw;
            float y2 = pcy + 0.5f * ph;
            x1 = fminf(fmaxf(x1, 0.0f), wmax);
            y1 = fminf(fmaxf(y1, 0.0f), hmax);
            x2 = fminf(fmaxf(x2, 0.0f), wmax);
            y2 = fminf(fmaxf(y2, 0.0f), hmax);
            boxes[(size_t)b * PRE_TOP + sl] = make_float4(x1, y1, x2, y2);
        } else {
            boxes[(size_t)b * PRE_TOP + sl] = make_float4(0.f, 0.f, 0.f, 0.f);
        }
    }
}

__global__ void __launch_bounds__(1024) nms_k(const float4* __restrict__ boxes,
                                              float* __restrict__ out) {
    __shared__ float kx1[POST_TOP], ky1[POST_TOP], kx2[POST_TOP], ky2[POST_TOP], kar[POST_TOP];
    __shared__ float gx1[64], gy1[64], gx2[64], gy2[64], gar[64];
    __shared__ unsigned extw[2];
    __shared__ unsigned intraw[128];
    __shared__ unsigned long long s_keep;
    __shared__ int s_base, s_kc, s_done;
    int b = blockIdx.x, t = threadIdx.x;
    if (t == 0) { s_kc = 0; s_done = 0; }
    const float4* bb = boxes + (size_t)b * PRE_TOP;
    const int ngroups = (PRE_TOP + 63) / 64;

    for (int g = 0; g < ngroups; ++g) {
        __syncthreads();          // prev append + flags visible
        if (s_done) break;
        int gbase = g * 64;
        int gsz = min(64, PRE_TOP - gbase);
        if (t < gsz) {
            float4 v = bb[gbase + t];
            gx1[t] = v.x; gy1[t] = v.y; gx2[t] = v.z; gy2[t] = v.w;
            gar[t] = __fmul_rn(v.z - v.x + 1.0f, v.w - v.y + 1.0f);
        }
        if (t < 2) extw[t] = 0u;
        if (t < 128) intraw[t] = 0u;
        __syncthreads();

        int kc = s_kc;
        // external suppression vs kept list
        {
            int j = t >> 4, sub = t & 15;
            if (j < gsz) {
                float ax1 = gx1[j], ay1 = gy1[j], ax2 = gx2[j], ay2 = gy2[j], aar = gar[j];
                bool any = false;
                for (int kk = sub; kk < kc; kk += 16) {
                    if (sup_test(kx1[kk], ky1[kk], kx2[kk], ky2[kk], kar[kk],
                                 ax1, ay1, ax2, ay2, aar)) { any = true; break; }
                }
                if (any) atomicOr(&extw[j >> 5], 1u << (j & 31));
            }
        }
        // intra-group pairwise (jj earlier suppresses ll later)
        for (int p = t; p < 4096; p += 1024) {
            int jj = p >> 6, ll = p & 63;
            if (jj < ll && ll < gsz) {
                if (sup_test(gx1[jj], gy1[jj], gx2[jj], gy2[jj], gar[jj],
                             gx1[ll], gy1[ll], gx2[ll], gy2[ll], gar[ll])) {
                    atomicOr(&intraw[2 * jj + (ll >> 5)], 1u << (ll & 31));
                }
            }
        }
        __syncthreads();

        if (t == 0) {
            unsigned long long ext64 = (unsigned long long)extw[0] |
                                       ((unsigned long long)extw[1] << 32);
            unsigned long long valid = (gsz >= 64) ? ~0ull : ((1ull << gsz) - 1ull);
            unsigned long long alive = (~ext64) & valid;
            unsigned long long keep = 0ull;
            int kcc = s_kc;
            s_base = kcc;
            while (alive && kcc < POST_TOP) {
                int j = __ffsll((long long)alive) - 1;
                keep |= (1ull << j);
                ++kcc;
                unsigned long long row = (unsigned long long)intraw[2 * j] |
                                         ((unsigned long long)intraw[2 * j + 1] << 32);
                alive &= ~row;
                alive &= ~(1ull << j);
            }
            s_keep = keep;
            s_kc = kcc;
            if (kcc >= POST_TOP) s_done = 1;
        }
        __syncthreads();

        if (t < gsz && ((s_keep >> t) & 1ull)) {
            int rank = __popcll(s_keep & ((1ull << t) - 1ull));
            int slot = s_base + rank;
            kx1[slot] = gx1[t]; ky1[slot] = gy1[t];
            kx2[slot] = gx2[t]; ky2[slot] = gy2[t]; kar[slot] = gar[t];
            float* o = out + (size_t)(b * POST_TOP + slot) * 5;
            o[0] = (float)b; o[1] = gx1[t]; o[2] = gy1[t]; o[3] = gx2[t]; o[4] = gy2[t];
        }
    }
    __syncthreads();
    for (int sl = s_kc + t; sl < POST_TOP; sl += 1024) {
        float* o = out + (size_t)(b * POST_TOP + sl) * 5;
        o[0] = (float)b; o[1] = 0.f; o[2] = 0.f; o[3] = 0.f; o[4] = 0.f;
    }
}

// ---------- launch ----------

extern "C" void kernel_launch(void* const* d_in, const int* in_sizes, int n_in,
                              void* d_out, int out_size, void* d_ws, size_t ws_size,
                              hipStream_t stream) {
    const float* scores  = (const float*)d_in[0];   // (8, 18, 152, 152)
    const float* deltas  = (const float*)d_in[1];   // (8, 36, 152, 152)
    const float* im_info = (const float*)d_in[2];   // (8, 3)
    const float* anchors = (const float*)d_in[3];   // (9, 4)
    float* out = (float*)d_out;                     // (8, 300, 5)

    // workspace layout (bytes)
    unsigned* hist    = (unsigned*)d_ws;                                 // 8*4096*4 = 131072
    unsigned* cnt     = (unsigned*)((char*)d_ws + 131072);               // 8*32*4   = 1024
    unsigned* bucketT = (unsigned*)((char*)d_ws + 132096);               // 8*4      = 32
    uint2*    cand    = (uint2*)((char*)d_ws + 132160);                  // 8*8192*8 = 524288
    float4*   boxes   = (float4*)((char*)d_ws + 656448);                 // 8*6000*16= 768000
    // total ~1.42 MB

    zero_k<<<64, 256, 0, stream>>>((unsigned*)d_ws, (131072 + 1024 + 64) / 4);
    hist_k<<<dim3(64, B_), 256, 0, stream>>>(scores, hist);
    scan_k<<<B_, 1024, 0, stream>>>(hist, bucketT);
    compact_k<<<dim3(64, B_), 256, 0, stream>>>(scores, bucketT, cnt, cand);
    sort_k<<<B_, 1024, 0, stream>>>(cnt, cand, deltas, anchors, im_info, boxes);
    nms_k<<<B_, 1024, 0, stream>>>(boxes, out);
}